// Round 1
// baseline (570.442 us; speedup 1.0000x reference)
//
#include <hip/hip_runtime.h>

// ---------------------------------------------------------------------------
// 3-layer GCN (PyG GCNConv semantics, add_self_loops=False) on MI355X.
// Pipeline:
//   deg[dst]++  ->  dinv = rsqrt(deg)  ->  rowptr = exscan(deg)
//   fill CSR (csr_src, csr_w = dinv[src]*dinv[dst]) via atomic slot counters
//   L1: h = x@W1     ; g = CSR-gather(h)+b1 -> BN -> ReLU
//   L2: h = g@W2     ; g = CSR-gather(h)+b2 -> BN -> ReLU
//   L3: h = g@W3(40) ; out = CSR-gather(h)+b3
// All fp32. CSR gather = one wave per node, lane = feature (coalesced 256B
// row reads of h, no float atomics -> deterministic up to fill order).
// ---------------------------------------------------------------------------

constexpr int SCAN_T = 256;
constexpr int SCAN_E = 8;
constexpr int SCAN_B = SCAN_T * SCAN_E; // 2048 elems per scan block

__global__ __launch_bounds__(256) void k_count_deg(const int* __restrict__ dst,
                                                   int* __restrict__ deg, int E) {
  int e = blockIdx.x * 256 + threadIdx.x;
  if (e < E) atomicAdd(&deg[dst[e]], 1);
}

__global__ __launch_bounds__(256) void k_dinv(const int* __restrict__ deg,
                                              float* __restrict__ dinv, int N) {
  int i = blockIdx.x * 256 + threadIdx.x;
  if (i < N) {
    int d = deg[i];
    dinv[i] = (d > 0) ? rsqrtf((float)d) : 0.f;
  }
}

// per-block exclusive scan of deg -> pre (rowptr w/o block offsets), block sums -> bsum
__global__ __launch_bounds__(SCAN_T) void k_scan1(const int* __restrict__ deg,
                                                  int* __restrict__ pre,
                                                  int* __restrict__ bsum, int N) {
  __shared__ int ls[SCAN_T];
  int t = threadIdx.x;
  int base = blockIdx.x * SCAN_B + t * SCAN_E;
  int v[SCAN_E];
  int s = 0;
#pragma unroll
  for (int j = 0; j < SCAN_E; ++j) {
    int idx = base + j;
    v[j] = (idx < N) ? deg[idx] : 0;
    s += v[j];
  }
  ls[t] = s;
  __syncthreads();
  for (int off = 1; off < SCAN_T; off <<= 1) {
    int x = 0;
    if (t >= off) x = ls[t - off];
    __syncthreads();
    ls[t] += x;
    __syncthreads();
  }
  if (t == SCAN_T - 1) bsum[blockIdx.x] = ls[t];
  int run = (t > 0) ? ls[t - 1] : 0;
#pragma unroll
  for (int j = 0; j < SCAN_E; ++j) {
    int idx = base + j;
    if (idx < N) pre[idx] = run;
    run += v[j];
  }
}

// single-block exclusive scan of block sums (nb <= 256)
__global__ __launch_bounds__(SCAN_T) void k_scan2(int* __restrict__ bsum, int nb) {
  __shared__ int ls[SCAN_T];
  int t = threadIdx.x;
  ls[t] = (t < nb) ? bsum[t] : 0;
  __syncthreads();
  for (int off = 1; off < SCAN_T; off <<= 1) {
    int x = 0;
    if (t >= off) x = ls[t - off];
    __syncthreads();
    ls[t] += x;
    __syncthreads();
  }
  if (t < nb) bsum[t] = (t > 0) ? ls[t - 1] : 0;
}

__global__ __launch_bounds__(256) void k_scan3(int* __restrict__ rowptr,
                                               const int* __restrict__ bsum,
                                               int N, int E) {
  int i = blockIdx.x * 256 + threadIdx.x;
  if (i < N) rowptr[i] += bsum[i / SCAN_B];
  if (i == 0) rowptr[N] = E;
}

__global__ __launch_bounds__(256) void k_fill(const int* __restrict__ src,
                                              const int* __restrict__ dst,
                                              const float* __restrict__ dinv,
                                              const int* __restrict__ rowptr,
                                              int* __restrict__ fillc,
                                              int* __restrict__ csr_src,
                                              float* __restrict__ csr_w, int E) {
  int e = blockIdx.x * 256 + threadIdx.x;
  if (e >= E) return;
  int d = dst[e], s = src[e];
  int slot = atomicAdd(&fillc[d], 1);
  int p = rowptr[d] + slot;
  csr_src[p] = s;
  csr_w[p] = dinv[s] * dinv[d];
}

// H[N,F] = X[N,K] @ W[K,F].  One wave per row (lane = out feature), W staged
// in LDS once per block, 4 rows staged in LDS per iteration, grid-stride.
template <int K, int F>
__global__ __launch_bounds__(256) void k_gemm(const float* __restrict__ X,
                                              const float* __restrict__ W,
                                              float* __restrict__ H, int N) {
  __shared__ float Wl[K * F];
  __shared__ float Xl[4][K];
  for (int i = threadIdx.x; i < K * F; i += 256) Wl[i] = W[i];
  int wv = threadIdx.x >> 6, lane = threadIdx.x & 63;
  for (int row0 = blockIdx.x * 4; row0 < N; row0 += gridDim.x * 4) {
    __syncthreads();  // Wl visible (1st iter) / previous Xl reads done
    for (int i = threadIdx.x; i < 4 * K; i += 256) {
      int r = row0 + i / K;
      Xl[i / K][i % K] = (r < N) ? X[(size_t)r * K + (i % K)] : 0.f;
    }
    __syncthreads();
    int row = row0 + wv;
    if (row < N && lane < F) {
      float acc = 0.f;
#pragma unroll
      for (int k = 0; k < K; ++k) acc = fmaf(Xl[wv][k], Wl[k * F + lane], acc);
      H[(size_t)row * F + lane] = acc;
    }
  }
}

// G[i,:] = BN/ReLU( sum_{p in rowptr[i]..} csr_w[p] * H[csr_src[p],:] + bias )
template <int F, bool BNR>
__global__ __launch_bounds__(256) void k_agg(const float* __restrict__ H,
                                             float* __restrict__ G,
                                             const int* __restrict__ rowptr,
                                             const int* __restrict__ csr_src,
                                             const float* __restrict__ csr_w,
                                             const float* __restrict__ bias,
                                             const float* __restrict__ gam,
                                             const float* __restrict__ bet,
                                             const float* __restrict__ mu,
                                             const float* __restrict__ var, int N) {
  int node = (blockIdx.x * 256 + threadIdx.x) >> 6;
  int lane = threadIdx.x & 63;
  if (node >= N) return;
  int p0 = rowptr[node], p1 = rowptr[node + 1];
  if (lane < F) {
    float acc = 0.f;
    for (int p = p0; p < p1; ++p) {
      int s = csr_src[p];
      float w = csr_w[p];
      acc = fmaf(w, H[(size_t)s * F + lane], acc);
    }
    float y = acc + bias[lane];
    if (BNR) {
      y = (y - mu[lane]) * rsqrtf(var[lane] + 1e-5f) * gam[lane] + bet[lane];
      y = fmaxf(y, 0.f);
    }
    G[(size_t)node * F + lane] = y;
  }
}

extern "C" void kernel_launch(void* const* d_in, const int* in_sizes, int n_in,
                              void* d_out, int out_size, void* d_ws, size_t ws_size,
                              hipStream_t stream) {
  const float* x  = (const float*)d_in[0];
  const int*   ei = (const int*)d_in[1];
  const float* W1 = (const float*)d_in[2];
  const float* b1 = (const float*)d_in[3];
  const float* W2 = (const float*)d_in[4];
  const float* b2 = (const float*)d_in[5];
  const float* W3 = (const float*)d_in[6];
  const float* b3 = (const float*)d_in[7];
  const float* g1 = (const float*)d_in[8];
  const float* be1 = (const float*)d_in[9];
  const float* m1 = (const float*)d_in[10];
  const float* v1 = (const float*)d_in[11];
  const float* g2 = (const float*)d_in[12];
  const float* be2 = (const float*)d_in[13];
  const float* m2 = (const float*)d_in[14];
  const float* v2 = (const float*)d_in[15];

  const int N = in_sizes[0] / 128;  // 100000
  const int E = in_sizes[1] / 2;    // 1000000
  const int* src = ei;
  const int* dst = ei + E;

  // ---- workspace layout (512B aligned slices) ----
  char* w = (char*)d_ws;
  size_t off = 0;
  auto take = [&](size_t bytes) -> void* {
    void* p = w + off;
    off += (bytes + 511) & ~size_t(511);
    return p;
  };
  int*   deg     = (int*)take((size_t)N * 4);
  int*   fillc   = (int*)take((size_t)N * 4);
  size_t zeroB   = off;  // deg + fillc are contiguous from 0
  int*   rowptr  = (int*)take(((size_t)N + 1) * 4);
  float* dinv    = (float*)take((size_t)N * 4);
  int*   bsum    = (int*)take((size_t)SCAN_T * 4);
  int*   csr_src = (int*)take((size_t)E * 4);
  float* csr_w   = (float*)take((size_t)E * 4);
  float* bufA    = (float*)take((size_t)N * 64 * 4);
  float* bufB    = (float*)take((size_t)N * 64 * 4);
  if (off > ws_size) return;  // workspace too small — fail loudly via validation

  const int nb = (N + SCAN_B - 1) / SCAN_B;  // 49 for N=100000

  hipMemsetAsync(d_ws, 0, zeroB, stream);
  k_count_deg<<<(E + 255) / 256, 256, 0, stream>>>(dst, deg, E);
  k_dinv<<<(N + 255) / 256, 256, 0, stream>>>(deg, dinv, N);
  k_scan1<<<nb, SCAN_T, 0, stream>>>(deg, rowptr, bsum, N);
  k_scan2<<<1, SCAN_T, 0, stream>>>(bsum, nb);
  k_scan3<<<(N + 255) / 256, 256, 0, stream>>>(rowptr, bsum, N, E);
  k_fill<<<(E + 255) / 256, 256, 0, stream>>>(src, dst, dinv, rowptr, fillc,
                                              csr_src, csr_w, E);

  // layer 1
  k_gemm<128, 64><<<2048, 256, 0, stream>>>(x, W1, bufA, N);
  k_agg<64, true><<<(N + 3) / 4, 256, 0, stream>>>(bufA, bufB, rowptr, csr_src,
                                                   csr_w, b1, g1, be1, m1, v1, N);
  // layer 2
  k_gemm<64, 64><<<2048, 256, 0, stream>>>(bufB, W2, bufA, N);
  k_agg<64, true><<<(N + 3) / 4, 256, 0, stream>>>(bufA, bufB, rowptr, csr_src,
                                                   csr_w, b2, g2, be2, m2, v2, N);
  // output layer
  k_gemm<64, 40><<<2048, 256, 0, stream>>>(bufB, W3, bufA, N);
  k_agg<40, false><<<(N + 3) / 4, 256, 0, stream>>>(
      bufA, (float*)d_out, rowptr, csr_src, csr_w, b3, nullptr, nullptr, nullptr,
      nullptr, N);
}